// Round 4
// baseline (337.609 us; speedup 1.0000x reference)
//
#include <hip/hip_runtime.h>
#include <stdint.h>

#define B_ 32
#define E_ 256
#define L_ 2048
#define D_ 256

#define BE 128             // e-rows per block
#define BD 256             // d-cols per block (full D)
#define BK 32              // k per step
#define KS 4               // k-split factor
#define KCHUNK (L_ / KS)   // 512
#define NKT (KCHUNK / BK)  // 16 k-steps per block

typedef __attribute__((ext_vector_type(4))) float  f32x4;
typedef __attribute__((ext_vector_type(4))) short  s16x4;
typedef __attribute__((ext_vector_type(8))) short  s16x8;

// fp32 -> (hi, lo) bf16 pair. hi = truncated bf16(x); lo = bf16(x - hi).
__device__ __forceinline__ void cvt_hilo1(float x, short &h, short &l) {
    unsigned u = __builtin_bit_cast(unsigned, x);
    h = (short)(u >> 16);
    float hf = __builtin_bit_cast(float, u & 0xFFFF0000u);
    unsigned r = __builtin_bit_cast(unsigned, x - hf);
    l = (short)(r >> 16);
}

__global__ void zero_out_kernel(f32x4* __restrict__ out) {
    out[(size_t)blockIdx.x * 256 + threadIdx.x] = f32x4{0.f, 0.f, 0.f, 0.f};
}

// ---- A (emap): coalesced wave loads of this wave's private 64e x 32k slice ----
// instr i: 8 rows x 128B (8 x 128B segments); lane holds row i*8+arow, k-quad akq.
#define LOADA(RA, K0)                                                          \
    {                                                                          \
        _Pragma("unroll")                                                      \
        for (int i = 0; i < 8; ++i)                                            \
            RA[i] = *(const f32x4*)(AgW + (size_t)(i * 8 + arow) * L_ + (K0) + akq * 4); \
    }

// ---- B (doc): direct fragment gather, 4x64B segments per instr ----
#define LOADB(PB, K0)                                                          \
    {                                                                          \
        _Pragma("unroll")                                                      \
        for (int ni = 0; ni < 4; ++ni)                                         \
            _Pragma("unroll")                                                  \
            for (int j = 0; j < 8; ++j)                                        \
                PB[ni][j] = Sg[(size_t)((K0) + kg * 8 + j) * D_ + dq + ni * 16 + ml]; \
    }

// convert + write A into this wave's PRIVATE LDS region (no barrier needed).
// write slot s = arow*8 + (akq ^ (arow&6)) is a lane-bijection -> conflict-free.
#define CVTWRITE_A(AW, RA)                                                     \
    {                                                                          \
        _Pragma("unroll")                                                      \
        for (int i = 0; i < 8; ++i) {                                          \
            s16x4 h, l;                                                        \
            _Pragma("unroll")                                                  \
            for (int q = 0; q < 4; ++q) { short hh, ll; cvt_hilo1(RA[i][q], hh, ll); h[q] = hh; l[q] = ll; } \
            *(s16x4*)&(AW)[i * 256 + awoff]        = h;                        \
            *(s16x4*)&(AW)[i * 256 + awoff + 2048] = l;                        \
        }                                                                      \
    }

// convert B prefetch registers into MFMA fragments
#define CVT_B(BH, BL, PB)                                                      \
    {                                                                          \
        _Pragma("unroll")                                                      \
        for (int ni = 0; ni < 4; ++ni)                                         \
            _Pragma("unroll")                                                  \
            for (int j = 0; j < 8; ++j) {                                      \
                short hh, ll; cvt_hilo1(PB[ni][j], hh, ll);                    \
                BH[ni][j] = hh; BL[ni][j] = ll;                                \
            }                                                                  \
    }

// ---- one k-step, entirely wave-local: no s_barrier anywhere ----
#define STEP(K, AW)                                                            \
    {                                                                          \
        CVTWRITE_A(AW, ra)                                                     \
        if ((K) + 1 < NKT) LOADA(ra, ((K) + 1) * BK)                           \
        s16x8 bh[4], bl[4];                                                    \
        CVT_B(bh, bl, pbv)                                                     \
        if ((K) + 1 < NKT) LOADB(pbv, ((K) + 1) * BK)                          \
        __builtin_amdgcn_s_setprio(1);                                         \
        _Pragma("unroll")                                                      \
        for (int mi = 0; mi < 4; ++mi) {                                       \
            const s16x8 ah = *(const s16x8*)&(AW)[aoff[mi]];                   \
            const s16x8 al = *(const s16x8*)&(AW)[aoff[mi] + 2048];            \
            _Pragma("unroll")                                                  \
            for (int ni = 0; ni < 4; ++ni) {                                   \
                acc[mi][ni] = __builtin_amdgcn_mfma_f32_16x16x32_bf16(ah, bh[ni], acc[mi][ni], 0, 0, 0); \
                acc[mi][ni] = __builtin_amdgcn_mfma_f32_16x16x32_bf16(ah, bl[ni], acc[mi][ni], 0, 0, 0); \
                acc[mi][ni] = __builtin_amdgcn_mfma_f32_16x16x32_bf16(al, bh[ni], acc[mi][ni], 0, 0, 0); \
            }                                                                  \
        }                                                                      \
        __builtin_amdgcn_s_setprio(0);                                         \
    }

__global__ __launch_bounds__(512, 2)
void mean_pool_kernel(const float* __restrict__ doc,
                      const float* __restrict__ emap,
                      const float* __restrict__ lens,
                      float* __restrict__ out) {
    // 8 waves x 2 buffers x 8KB: wave-PRIVATE A tiles (hi 4KB | lo 4KB each).
    __shared__ __align__(16) short Apriv[8][2][4096];   // 128 KB total

    const int t  = threadIdx.x;
    const int bi = blockIdx.x;
    // XCD pairing (round-3 verified: FETCH 98->66MB): blocks sharing doc/emap
    // slices land on the same XCD. Bijective over 0..255.
    const int r   = bi & 7;
    const int q   = bi >> 3;
    const int ks  = r & 3;
    const int b   = (q >> 1) * 2 + (r >> 2);
    const int e0  = (q & 1) * BE;

    const float* Ag = emap + ((size_t)b * E_ + e0) * L_ + ks * KCHUNK;
    const float* Sg = doc  + (size_t)b * L_ * D_ + (size_t)ks * KCHUNK * D_;

    // ---- wave/MFMA coords: 8 waves as 2(e) x 4(d), wave tile 64x64 ----
    const int lane = t & 63;
    const int w    = t >> 6;
    const int eo   = (w & 1) * 64;
    const int dq   = (w >> 1) * 64;
    const int ml   = lane & 15;
    const int kg   = lane >> 4;

    const float* AgW = Ag + (size_t)eo * L_;   // this wave's 64 e-rows

    // A staging lane coords (wave-local slice [64 rows][32 k])
    const int arow = lane >> 3;   // 0..7: row within 8-row chunk
    const int akq  = lane & 7;    // k-quad (4 floats = 16B)
    // linear-per-lane write slot, XOR'd so frag reads are <=2-way banked
    const int awoff = (arow * 8 + (akq ^ (arow & 6))) * 4;   // shorts

    // frag read offsets (element (row, kq=2kg..2kg+1) per write mapping above)
    int aoff[4];
    #pragma unroll
    for (int mi = 0; mi < 4; ++mi) {
        const int row = mi * 16 + ml;
        const int r7  = row & 7;
        const int slot = r7 * 8 + ((2 * kg) ^ (r7 & 6));
        aoff[mi] = (row >> 3) * 256 + slot * 4;   // shorts; 16B-aligned (slot even)
    }

    short* const A0 = &Apriv[w][0][0];
    short* const A1 = &Apriv[w][1][0];

    f32x4 acc[4][4] = {};
    f32x4 ra[8];          // A prefetch (1 step ahead)
    float pbv[4][8];      // B prefetch (1 step ahead), fully static-indexed

    // ---- prologue ----
    LOADA(ra, 0)
    LOADB(pbv, 0)

    // ---- main loop: barrier-free, waves free-run ----
    for (int kt = 0; kt < NKT; kt += 2) {
        STEP(kt,     A0)
        STEP(kt + 1, A1)
    }

    // ---- epilogue: divide by entity_lens, accumulate k-split partials ----
    const float* lensB = lens + b * E_ + e0;
    #pragma unroll
    for (int mi = 0; mi < 4; ++mi) {
        #pragma unroll
        for (int rr = 0; rr < 4; ++rr) {
            const int er = eo + mi * 16 + kg * 4 + rr;
            const float lv = lensB[er];
            #pragma unroll
            for (int ni = 0; ni < 4; ++ni)
                atomicAdd(&out[((size_t)(b * E_ + e0 + er)) * D_ + dq + ni * 16 + ml],
                          acc[mi][ni][rr] / lv);
        }
    }
}

extern "C" void kernel_launch(void* const* d_in, const int* in_sizes, int n_in,
                              void* d_out, int out_size, void* d_ws, size_t ws_size,
                              hipStream_t stream) {
    const float* doc  = (const float*)d_in[0];   // [32][2048][256]
    const float* emap = (const float*)d_in[1];   // [32][256][2048]
    const float* lens = (const float*)d_in[2];   // [32][256]
    float* out = (float*)d_out;                  // [32][256][256]

    // zero the output (harness poisons it), then accumulate partials
    zero_out_kernel<<<dim3(out_size / (4 * 256)), dim3(256), 0, stream>>>((f32x4*)out);

    dim3 grid(B_ * (E_ / BE) * (D_ / BD) * KS);  // 256 workgroups, 1 per CU
    dim3 block(512);
    hipLaunchKernelGGL(mean_pool_kernel, grid, block, 0, stream,
                       doc, emap, lens, out);
}

// Round 5
// 182.361 us; speedup vs baseline: 1.8513x; 1.8513x over previous
//
#include <hip/hip_runtime.h>
#include <stdint.h>

#define B_ 32
#define E_ 256
#define L_ 2048
#define D_ 256

#define BE 128             // e-rows per block
#define BD 256             // d-cols per block (full D)
#define BK 32              // k per step
#define KS 4               // k-split factor
#define KCHUNK (L_ / KS)   // 512
#define NKT (KCHUNK / BK)  // 16 k-steps per block

typedef __attribute__((ext_vector_type(4))) float  f32x4;
typedef __attribute__((ext_vector_type(8))) short  s16x8;

// fp32 -> (hi, lo) bf16 pair. hi = truncated bf16(x); lo = bf16(x - hi).
__device__ __forceinline__ void cvt_hilo1(float x, short &h, short &l) {
    unsigned u = __builtin_bit_cast(unsigned, x);
    h = (short)(u >> 16);
    float hf = __builtin_bit_cast(float, u & 0xFFFF0000u);
    unsigned r = __builtin_bit_cast(unsigned, x - hf);
    l = (short)(r >> 16);
}

__global__ void zero_out_kernel(f32x4* __restrict__ out) {
    out[(size_t)blockIdx.x * 256 + threadIdx.x] = f32x4{0.f, 0.f, 0.f, 0.f};
}

// direct global->LDS DMA, 16B per lane, dest = wave-uniform base + lane*16
__device__ __forceinline__ void gload16(const float* g, float* l) {
    __builtin_amdgcn_global_load_lds(
        (const __attribute__((address_space(1))) void*)g,
        (__attribute__((address_space(3))) void*)l, 16, 0, 0);
}

// ---- issue one k-tile: 6 global_load_lds per wave (A:2, B:4), fp32 ----
// A LDS [128 rows][32 k]: content[r][q] = global[r][q ^ (r&7)]  (16B quads)
// B LDS [32 k][256 d]:    content[k][dw] = global[k][dw ^ (((k>>3)&3)<<4)] (words)
#define ISSUE_TILE(AB, BB, K0)                                                 \
    {                                                                          \
        _Pragma("unroll")                                                      \
        for (int i = 0; i < 2; ++i) {                                          \
            const int r_ = w * 16 + i * 8 + (lane >> 3);                       \
            const int q_ = (lane & 7) ^ (r_ & 7);                              \
            gload16(Ag + (size_t)r_ * L_ + (K0) + q_ * 4, (AB) + (w * 2 + i) * 256); \
        }                                                                      \
        _Pragma("unroll")                                                      \
        for (int i = 0; i < 4; ++i) {                                          \
            const int k_ = w * 4 + i;                                          \
            const int ds_ = 4 * (lane ^ (((k_ >> 3) & 3) << 2));               \
            gload16(Sg + (size_t)((K0) + k_) * D_ + ds_, (BB) + k_ * 256);     \
        }                                                                      \
    }

// ---- compute one staged tile: LDS fp32 reads -> cvt hi/lo -> 48 MFMAs ----
#define COMPUTE(AB, BB)                                                        \
    {                                                                          \
        f32x4 afl[4], afh[4];                                                  \
        _Pragma("unroll")                                                      \
        for (int mi = 0; mi < 4; ++mi) {                                       \
            const int row_ = eo + mi * 16 + ml;                                \
            afl[mi] = *(const f32x4*)((AB) + row_ * 32 + a_o1);                \
            afh[mi] = *(const f32x4*)((AB) + row_ * 32 + a_o2);                \
        }                                                                      \
        float bfv[4][8];                                                       \
        _Pragma("unroll")                                                      \
        for (int ni = 0; ni < 4; ++ni)                                         \
            _Pragma("unroll")                                                  \
            for (int j = 0; j < 8; ++j)                                        \
                bfv[ni][j] = (BB)[b_o[ni] + j * 256];                          \
        s16x8 bh[4], bl[4];                                                    \
        _Pragma("unroll")                                                      \
        for (int ni = 0; ni < 4; ++ni)                                         \
            _Pragma("unroll")                                                  \
            for (int j = 0; j < 8; ++j) {                                      \
                short hh, ll; cvt_hilo1(bfv[ni][j], hh, ll);                   \
                bh[ni][j] = hh; bl[ni][j] = ll;                                \
            }                                                                  \
        __builtin_amdgcn_s_setprio(1);                                         \
        _Pragma("unroll")                                                      \
        for (int mi = 0; mi < 4; ++mi) {                                       \
            s16x8 ah, al;                                                      \
            _Pragma("unroll")                                                  \
            for (int q = 0; q < 4; ++q) { short hh, ll; cvt_hilo1(afl[mi][q], hh, ll); ah[q] = hh; al[q] = ll; } \
            _Pragma("unroll")                                                  \
            for (int q = 0; q < 4; ++q) { short hh, ll; cvt_hilo1(afh[mi][q], hh, ll); ah[4 + q] = hh; al[4 + q] = ll; } \
            _Pragma("unroll")                                                  \
            for (int ni = 0; ni < 4; ++ni) {                                   \
                acc[mi][ni] = __builtin_amdgcn_mfma_f32_16x16x32_bf16(ah, bh[ni], acc[mi][ni], 0, 0, 0); \
                acc[mi][ni] = __builtin_amdgcn_mfma_f32_16x16x32_bf16(ah, bl[ni], acc[mi][ni], 0, 0, 0); \
                acc[mi][ni] = __builtin_amdgcn_mfma_f32_16x16x32_bf16(al, bh[ni], acc[mi][ni], 0, 0, 0); \
            }                                                                  \
        }                                                                      \
        __builtin_amdgcn_s_setprio(0);                                         \
    }

// ---- full steady-state step: issue k+2, compute k, counted wait, barrier ----
#define STEP_FULL(ABC, BBC, ABN, BBN)                                          \
    {                                                                          \
        ISSUE_TILE(ABN, BBN, knext)                                            \
        knext += BK;                                                           \
        COMPUTE(ABC, BBC)                                                      \
        asm volatile("s_waitcnt vmcnt(6)" ::: "memory");                       \
        __builtin_amdgcn_s_barrier();                                          \
        asm volatile("" ::: "memory");                                         \
    }

__global__ __launch_bounds__(512, 2)
void mean_pool_kernel(const float* __restrict__ doc,
                      const float* __restrict__ emap,
                      const float* __restrict__ lens,
                      float* __restrict__ out) {
    // triple-buffered fp32 tiles: 3 x (A 16KB + B 32KB) = 144 KB
    __shared__ __align__(16) float Asm[3][BE * BK];
    __shared__ __align__(16) float Bsm[3][BK * BD];

    const int t  = threadIdx.x;
    const int bi = blockIdx.x;
    // XCD pairing (R3-verified: FETCH 98->66MB). Bijective over 0..255.
    const int r_  = bi & 7;
    const int q_  = bi >> 3;
    const int ks  = r_ & 3;
    const int b   = (q_ >> 1) * 2 + (r_ >> 2);
    const int e0  = (q_ & 1) * BE;

    const float* Ag = emap + ((size_t)b * E_ + e0) * L_ + ks * KCHUNK;
    const float* Sg = doc  + (size_t)b * L_ * D_ + (size_t)ks * KCHUNK * D_;

    // ---- wave/MFMA coords: 8 waves as 2(e) x 4(d), wave tile 64x64 ----
    const int lane = t & 63;
    const int w    = t >> 6;
    const int eo   = (w & 1) * 64;
    const int dq   = (w >> 1) * 64;
    const int ml   = lane & 15;
    const int kg   = lane >> 4;

    // A frag read offsets (floats within a 32-float row), swizzle q^(row&7)
    const int a_o1 = (((2 * kg)    ) ^ (ml & 7)) * 4;
    const int a_o2 = (((2 * kg) | 1) ^ (ml & 7)) * 4;
    // B frag read bases (floats): word = k*256 + (d ^ (kg<<4)), k = kg*8+j
    int b_o[4];
    #pragma unroll
    for (int ni = 0; ni < 4; ++ni)
        b_o[ni] = kg * 2048 + dq + ((ni ^ kg) * 16) + ml;

    float* const A0 = &Asm[0][0];  float* const B0 = &Bsm[0][0];
    float* const A1 = &Asm[1][0];  float* const B1 = &Bsm[1][0];
    float* const A2 = &Asm[2][0];  float* const B2 = &Bsm[2][0];

    f32x4 acc[4][4] = {};

    // ---- prologue: tiles 0,1 in flight; wait tile 0 only ----
    ISSUE_TILE(A0, B0, 0)
    ISSUE_TILE(A1, B1, BK)
    asm volatile("s_waitcnt vmcnt(6)" ::: "memory");
    __builtin_amdgcn_s_barrier();
    asm volatile("" ::: "memory");

    int knext = 2 * BK;

    // ---- steps 0..13 (full), buffers cycle 0,1,2 ----
    #pragma unroll 1
    for (int g = 0; g < 4; ++g) {
        STEP_FULL(A0, B0, A2, B2)
        STEP_FULL(A1, B1, A0, B0)
        STEP_FULL(A2, B2, A1, B1)
    }
    STEP_FULL(A0, B0, A2, B2)      // kt=12, issues tile 14
    STEP_FULL(A1, B1, A0, B0)      // kt=13, issues tile 15

    // ---- step 14: last wait drains everything ----
    COMPUTE(A2, B2)
    asm volatile("s_waitcnt vmcnt(0)" ::: "memory");
    __builtin_amdgcn_s_barrier();
    asm volatile("" ::: "memory");

    // ---- step 15 ----
    COMPUTE(A0, B0)

    // ---- epilogue: divide by entity_lens, accumulate k-split partials ----
    const float* lensB = lens + b * E_ + e0;
    #pragma unroll
    for (int mi = 0; mi < 4; ++mi) {
        #pragma unroll
        for (int rr = 0; rr < 4; ++rr) {
            const int er = eo + mi * 16 + kg * 4 + rr;
            const float lv = lensB[er];
            #pragma unroll
            for (int ni = 0; ni < 4; ++ni)
                atomicAdd(&out[((size_t)(b * E_ + e0 + er)) * D_ + dq + ni * 16 + ml],
                          acc[mi][ni][rr] / lv);
        }
    }
}

extern "C" void kernel_launch(void* const* d_in, const int* in_sizes, int n_in,
                              void* d_out, int out_size, void* d_ws, size_t ws_size,
                              hipStream_t stream) {
    const float* doc  = (const float*)d_in[0];   // [32][2048][256]
    const float* emap = (const float*)d_in[1];   // [32][256][2048]
    const float* lens = (const float*)d_in[2];   // [32][256]
    float* out = (float*)d_out;                  // [32][256][256]

    // zero the output (harness poisons it), then accumulate partials
    zero_out_kernel<<<dim3(out_size / (4 * 256)), dim3(256), 0, stream>>>((f32x4*)out);

    dim3 grid(B_ * (E_ / BE) * (D_ / BD) * KS);  // 256 workgroups, 1 per CU
    dim3 block(512);
    hipLaunchKernelGGL(mean_pool_kernel, grid, block, 0, stream,
                       doc, emap, lens, out);
}

// Round 6
// 172.743 us; speedup vs baseline: 1.9544x; 1.0557x over previous
//
#include <hip/hip_runtime.h>
#include <stdint.h>

#define B_ 32
#define E_ 256
#define L_ 2048
#define D_ 256

#define BE 128             // e-rows per block
#define BD 256             // d-cols per block (full D)
#define BK 32              // k per step
#define KS 4               // k-split factor
#define KCHUNK (L_ / KS)   // 512
#define NKT (KCHUNK / BK)  // 16 k-steps per block

#define SLAB_FLOATS ((size_t)B_ * E_ * D_)          // 2,097,152 floats = 8 MB
#define WS_NEED     (KS * SLAB_FLOATS * 4)          // 32 MB

typedef __attribute__((ext_vector_type(4))) float  f32x4;
typedef __attribute__((ext_vector_type(8))) short  s16x8;

// fp32 -> (hi, lo) bf16 pair. hi = truncated bf16(x); lo = bf16(x - hi).
__device__ __forceinline__ void cvt_hilo1(float x, short &h, short &l) {
    unsigned u = __builtin_bit_cast(unsigned, x);
    h = (short)(u >> 16);
    float hf = __builtin_bit_cast(float, u & 0xFFFF0000u);
    unsigned r = __builtin_bit_cast(unsigned, x - hf);
    l = (short)(r >> 16);
}

__global__ void zero_out_kernel(f32x4* __restrict__ out) {
    out[(size_t)blockIdx.x * 256 + threadIdx.x] = f32x4{0.f, 0.f, 0.f, 0.f};
}

// ---- reduce: out[i] = (ws0[i]+ws1[i]+ws2[i]+ws3[i]) / lens[row] ----
__global__ __launch_bounds__(256)
void reduce_kernel(const f32x4* __restrict__ ws, const float* __restrict__ lens,
                   f32x4* __restrict__ out) {
    const size_t i = (size_t)blockIdx.x * 256 + threadIdx.x;   // f32x4 index
    const float lv = lens[i >> 6];                              // 64 f32x4 per (b,e) row
    f32x4 s0 = ws[i];
    f32x4 s1 = ws[i +     (SLAB_FLOATS / 4)];
    f32x4 s2 = ws[i + 2 * (SLAB_FLOATS / 4)];
    f32x4 s3 = ws[i + 3 * (SLAB_FLOATS / 4)];
    f32x4 r;
    #pragma unroll
    for (int c = 0; c < 4; ++c) r[c] = (s0[c] + s1[c] + s2[c] + s3[c]) / lv;
    out[i] = r;
}

// direct global->LDS DMA, 16B per lane, dest = wave-uniform base + lane*16
__device__ __forceinline__ void gload16(const float* g, float* l) {
    __builtin_amdgcn_global_load_lds(
        (const __attribute__((address_space(1))) void*)g,
        (__attribute__((address_space(3))) void*)l, 16, 0, 0);
}

// ---- issue one k-tile: 6 global_load_lds per wave (A:2, B:4), fp32 ----
// A LDS [128 rows][32 k]: content[r][q] = global[r][q ^ (r&7)]  (16B quads)
// B LDS [32 k][256 d]:    content[k][dw] = global[k][dw ^ (((k>>3)&3)<<4)] (words)
#define ISSUE_TILE(AB, BB, K0)                                                 \
    {                                                                          \
        _Pragma("unroll")                                                      \
        for (int i = 0; i < 2; ++i) {                                          \
            const int r_ = w * 16 + i * 8 + (lane >> 3);                       \
            const int q_ = (lane & 7) ^ (r_ & 7);                              \
            gload16(Ag + (size_t)r_ * L_ + (K0) + q_ * 4, (AB) + (w * 2 + i) * 256); \
        }                                                                      \
        _Pragma("unroll")                                                      \
        for (int i = 0; i < 4; ++i) {                                          \
            const int k_ = w * 4 + i;                                          \
            const int ds_ = 4 * (lane ^ (((k_ >> 3) & 3) << 2));               \
            gload16(Sg + (size_t)((K0) + k_) * D_ + ds_, (BB) + k_ * 256);     \
        }                                                                      \
    }

// ---- compute one staged tile: LDS fp32 reads -> cvt hi/lo -> 48 MFMAs ----
#define COMPUTE(AB, BB)                                                        \
    {                                                                          \
        f32x4 afl[4], afh[4];                                                  \
        _Pragma("unroll")                                                      \
        for (int mi = 0; mi < 4; ++mi) {                                       \
            const int row_ = eo + mi * 16 + ml;                                \
            afl[mi] = *(const f32x4*)((AB) + row_ * 32 + a_o1);                \
            afh[mi] = *(const f32x4*)((AB) + row_ * 32 + a_o2);                \
        }                                                                      \
        float bfv[4][8];                                                       \
        _Pragma("unroll")                                                      \
        for (int ni = 0; ni < 4; ++ni)                                         \
            _Pragma("unroll")                                                  \
            for (int j = 0; j < 8; ++j)                                        \
                bfv[ni][j] = (BB)[b_o[ni] + j * 256];                          \
        s16x8 bh[4], bl[4];                                                    \
        _Pragma("unroll")                                                      \
        for (int ni = 0; ni < 4; ++ni)                                         \
            _Pragma("unroll")                                                  \
            for (int j = 0; j < 8; ++j) {                                      \
                short hh, ll; cvt_hilo1(bfv[ni][j], hh, ll);                   \
                bh[ni][j] = hh; bl[ni][j] = ll;                                \
            }                                                                  \
        __builtin_amdgcn_s_setprio(1);                                         \
        _Pragma("unroll")                                                      \
        for (int mi = 0; mi < 4; ++mi) {                                       \
            s16x8 ah, al;                                                      \
            _Pragma("unroll")                                                  \
            for (int q = 0; q < 4; ++q) { short hh, ll; cvt_hilo1(afl[mi][q], hh, ll); ah[q] = hh; al[q] = ll; } \
            _Pragma("unroll")                                                  \
            for (int q = 0; q < 4; ++q) { short hh, ll; cvt_hilo1(afh[mi][q], hh, ll); ah[4 + q] = hh; al[4 + q] = ll; } \
            _Pragma("unroll")                                                  \
            for (int ni = 0; ni < 4; ++ni) {                                   \
                acc[mi][ni] = __builtin_amdgcn_mfma_f32_16x16x32_bf16(ah, bh[ni], acc[mi][ni], 0, 0, 0); \
                acc[mi][ni] = __builtin_amdgcn_mfma_f32_16x16x32_bf16(ah, bl[ni], acc[mi][ni], 0, 0, 0); \
                acc[mi][ni] = __builtin_amdgcn_mfma_f32_16x16x32_bf16(al, bh[ni], acc[mi][ni], 0, 0, 0); \
            }                                                                  \
        }                                                                      \
        __builtin_amdgcn_s_setprio(0);                                         \
    }

// ---- full steady-state step: issue k+2, compute k, counted wait, barrier ----
#define STEP_FULL(ABC, BBC, ABN, BBN)                                          \
    {                                                                          \
        ISSUE_TILE(ABN, BBN, knext)                                            \
        knext += BK;                                                           \
        COMPUTE(ABC, BBC)                                                      \
        asm volatile("s_waitcnt vmcnt(6)" ::: "memory");                       \
        __builtin_amdgcn_s_barrier();                                          \
        asm volatile("" ::: "memory");                                         \
    }

template <int WS>
__global__ __launch_bounds__(512, 2)
void mean_pool_kernel(const float* __restrict__ doc,
                      const float* __restrict__ emap,
                      const float* __restrict__ lens,
                      float* __restrict__ out,
                      float* __restrict__ wsp) {
    // triple-buffered fp32 tiles: 3 x (A 16KB + B 32KB) = 144 KB
    __shared__ __align__(16) float Asm[3][BE * BK];
    __shared__ __align__(16) float Bsm[3][BK * BD];

    const int t  = threadIdx.x;
    const int bi = blockIdx.x;
    // XCD pairing (R3-verified: FETCH 98->66MB). Bijective over 0..255.
    const int r_  = bi & 7;
    const int q_  = bi >> 3;
    const int ks  = r_ & 3;
    const int b   = (q_ >> 1) * 2 + (r_ >> 2);
    const int e0  = (q_ & 1) * BE;

    const float* Ag = emap + ((size_t)b * E_ + e0) * L_ + ks * KCHUNK;
    const float* Sg = doc  + (size_t)b * L_ * D_ + (size_t)ks * KCHUNK * D_;

    // ---- wave/MFMA coords: 8 waves as 2(e) x 4(d), wave tile 64x64 ----
    const int lane = t & 63;
    const int w    = t >> 6;
    const int eo   = (w & 1) * 64;
    const int dq   = (w >> 1) * 64;
    const int ml   = lane & 15;
    const int kg   = lane >> 4;

    // A frag read offsets (floats within a 32-float row), swizzle q^(row&7)
    const int a_o1 = (((2 * kg)    ) ^ (ml & 7)) * 4;
    const int a_o2 = (((2 * kg) | 1) ^ (ml & 7)) * 4;
    // B frag read bases (floats): word = k*256 + (d ^ (kg<<4)), k = kg*8+j
    int b_o[4];
    #pragma unroll
    for (int ni = 0; ni < 4; ++ni)
        b_o[ni] = kg * 2048 + dq + ((ni ^ kg) * 16) + ml;

    float* const A0 = &Asm[0][0];  float* const B0 = &Bsm[0][0];
    float* const A1 = &Asm[1][0];  float* const B1 = &Bsm[1][0];
    float* const A2 = &Asm[2][0];  float* const B2 = &Bsm[2][0];

    f32x4 acc[4][4] = {};

    // ---- prologue: tiles 0,1 in flight; wait tile 0 only ----
    ISSUE_TILE(A0, B0, 0)
    ISSUE_TILE(A1, B1, BK)
    asm volatile("s_waitcnt vmcnt(6)" ::: "memory");
    __builtin_amdgcn_s_barrier();
    asm volatile("" ::: "memory");

    int knext = 2 * BK;

    // ---- steps 0..13 (full), buffers cycle 0,1,2 ----
    #pragma unroll 1
    for (int g = 0; g < 4; ++g) {
        STEP_FULL(A0, B0, A2, B2)
        STEP_FULL(A1, B1, A0, B0)
        STEP_FULL(A2, B2, A1, B1)
    }
    STEP_FULL(A0, B0, A2, B2)      // kt=12, issues tile 14
    STEP_FULL(A1, B1, A0, B0)      // kt=13, issues tile 15

    // ---- step 14: last wait drains everything ----
    COMPUTE(A2, B2)
    asm volatile("s_waitcnt vmcnt(0)" ::: "memory");
    __builtin_amdgcn_s_barrier();
    asm volatile("" ::: "memory");

    // ---- step 15 ----
    COMPUTE(A0, B0)

    if (WS) {
        // ---- plain coalesced stores of partials into ws[ks][b][e][d] ----
        float* wsb = wsp + (size_t)ks * SLAB_FLOATS
                         + ((size_t)(b * E_ + e0)) * D_ + dq;
        #pragma unroll
        for (int mi = 0; mi < 4; ++mi) {
            #pragma unroll
            for (int rr = 0; rr < 4; ++rr) {
                const int er = eo + mi * 16 + kg * 4 + rr;
                #pragma unroll
                for (int ni = 0; ni < 4; ++ni)
                    wsb[(size_t)er * D_ + ni * 16 + ml] = acc[mi][ni][rr];
            }
        }
    } else {
        // ---- fallback: atomic accumulation (R5 path) ----
        const float* lensB = lens + b * E_ + e0;
        #pragma unroll
        for (int mi = 0; mi < 4; ++mi) {
            #pragma unroll
            for (int rr = 0; rr < 4; ++rr) {
                const int er = eo + mi * 16 + kg * 4 + rr;
                const float lv = lensB[er];
                #pragma unroll
                for (int ni = 0; ni < 4; ++ni)
                    atomicAdd(&out[((size_t)(b * E_ + e0 + er)) * D_ + dq + ni * 16 + ml],
                              acc[mi][ni][rr] / lv);
            }
        }
    }
}

extern "C" void kernel_launch(void* const* d_in, const int* in_sizes, int n_in,
                              void* d_out, int out_size, void* d_ws, size_t ws_size,
                              hipStream_t stream) {
    const float* doc  = (const float*)d_in[0];   // [32][2048][256]
    const float* emap = (const float*)d_in[1];   // [32][256][2048]
    const float* lens = (const float*)d_in[2];   // [32][256]
    float* out = (float*)d_out;                  // [32][256][256]
    float* ws  = (float*)d_ws;

    dim3 pgrid(B_ * (E_ / BE) * (D_ / BD) * KS);  // 256 workgroups
    dim3 pblock(512);

    if (ws_size >= (size_t)WS_NEED) {
        // no atomics: partials -> workspace slabs, then streaming reduce
        hipLaunchKernelGGL((mean_pool_kernel<1>), pgrid, pblock, 0, stream,
                           doc, emap, lens, out, ws);
        hipLaunchKernelGGL(reduce_kernel,
                           dim3((unsigned)(SLAB_FLOATS / 4 / 256)), dim3(256), 0, stream,
                           (const f32x4*)ws, lens, (f32x4*)out);
    } else {
        // fallback: proven atomic path
        zero_out_kernel<<<dim3(out_size / (4 * 256)), dim3(256), 0, stream>>>((f32x4*)out);
        hipLaunchKernelGGL((mean_pool_kernel<0>), pgrid, pblock, 0, stream,
                           doc, emap, lens, out, ws);
    }
}

// Round 7
// 171.073 us; speedup vs baseline: 1.9735x; 1.0098x over previous
//
#include <hip/hip_runtime.h>
#include <stdint.h>

#define B_ 32
#define E_ 256
#define L_ 2048
#define D_ 256

#define BE 64
#define BD 128
#define BK 64
#define KS 4                  // k-split factor
#define KCHUNK (L_ / KS)      // 512
#define NKT (KCHUNK / BK)     // 8 k-tiles per block

#define SLAB_FLOATS ((size_t)B_ * E_ * D_)          // 2,097,152 floats = 8 MB
#define WS_NEED     (KS * SLAB_FLOATS * 4)          // 32 MB

typedef __attribute__((ext_vector_type(2))) float  f32x2;
typedef __attribute__((ext_vector_type(4))) float  f32x4;
typedef __attribute__((ext_vector_type(4))) short  s16x4;
typedef __attribute__((ext_vector_type(8))) short  s16x8;

// fp32 -> (hi, lo) bf16 pair. hi = truncated bf16(x); lo = bf16(x - hi).
__device__ __forceinline__ void cvt_hilo1(float x, short &h, short &l) {
    unsigned u = __builtin_bit_cast(unsigned, x);
    h = (short)(u >> 16);
    float hf = __builtin_bit_cast(float, u & 0xFFFF0000u);
    unsigned r = __builtin_bit_cast(unsigned, x - hf);
    l = (short)(r >> 16);
}
__device__ __forceinline__ void cvt_hilo4(const f32x4 v, s16x4 &h, s16x4 &l) {
    #pragma unroll
    for (int i = 0; i < 4; ++i) { short hh, ll; cvt_hilo1(v[i], hh, ll); h[i] = hh; l[i] = ll; }
}

__global__ void zero_out_kernel(f32x4* __restrict__ out) {
    out[(size_t)blockIdx.x * 256 + threadIdx.x] = f32x4{0.f, 0.f, 0.f, 0.f};
}

// ---- reduce: out[i] = (ws0[i]+ws1[i]+ws2[i]+ws3[i]) / lens[row] ----
__global__ __launch_bounds__(256)
void reduce_kernel(const f32x4* __restrict__ ws, const float* __restrict__ lens,
                   f32x4* __restrict__ out) {
    const size_t i = (size_t)blockIdx.x * 256 + threadIdx.x;   // f32x4 index
    const float lv = lens[i >> 6];                              // 64 f32x4 per (b,e) row
    f32x4 s0 = ws[i];
    f32x4 s1 = ws[i +     (SLAB_FLOATS / 4)];
    f32x4 s2 = ws[i + 2 * (SLAB_FLOATS / 4)];
    f32x4 s3 = ws[i + 3 * (SLAB_FLOATS / 4)];
    f32x4 r;
    #pragma unroll
    for (int c = 0; c < 4; ++c) r[c] = (s0[c] + s1[c] + s2[c] + s3[c]) / lv;
    out[i] = r;
}

template <int WS>
__global__ __launch_bounds__(512, 6)
void mean_pool_kernel(const float* __restrict__ doc,
                      const float* __restrict__ emap,
                      const float* __restrict__ lens,
                      float* __restrict__ out,
                      float* __restrict__ wsp) {
    // A swizzle key: row&7.  B swizzle key: ((row>>1)&3)|(((row>>3)&1)<<2).
    // Both span all 8 col8 groups uniformly for BOTH the write lanes and the
    // read lanes -> all LDS ops at the 32-bank minimum cycle count.
    __shared__ __align__(16) short As_hi[BE][BK];
    __shared__ __align__(16) short As_lo[BE][BK];
    __shared__ __align__(16) short Bs_hi[BD][BK];   // doc^T tile: [d][k]
    __shared__ __align__(16) short Bs_lo[BD][BK];
    __shared__ float lens_s[BE];

    const int t   = threadIdx.x;
    const int blk = blockIdx.x;
    const int ks  = blk & 3;
    const int d0  = ((blk >> 2) & 1) * BD;
    const int e0  = ((blk >> 3) & 3) * BE;
    const int b   = blk >> 5;

    const float* Ag = emap + ((size_t)b * E_ + e0) * L_ + ks * KCHUNK;
    const float* Sg = doc  + (size_t)b * L_ * D_ + (size_t)ks * KCHUNK * D_ + d0;

    if (!WS && t < BE) lens_s[t] = lens[b * E_ + e0 + t];

    // A staging coords: 16 lanes per e-row (k-contiguous float4), rows t>>4 and +32
    const int a_c4 = t & 15;
    const int a_r  = t >> 4;
    // B staging coords: micro-tile 8k x 2d per thread
    const int db = t & 63;     // d-pair index (0..63) -> d = db*2, db == lane
    const int kb = t >> 6;     // k-group (0..7)       -> k = kb*8, kb == wave

    // wave coords: 8 waves as 2(e) x 4(d), wave tile 32e x 32d
    const int lane = t & 63;
    const int w    = t >> 6;
    const int eo   = (w & 1) * 32;
    const int dq   = (w >> 1) * 32;
    const int ml   = lane & 15;
    const int kg   = lane >> 4;

    f32x4 acc[2][2] = {};
    f32x4 pa[2];
    f32x2 pb[8];

    // preload tile 0
    #pragma unroll
    for (int rr = 0; rr < 2; ++rr)
        pa[rr] = *(const f32x4*)(Ag + (size_t)(a_r + rr * 32) * L_ + a_c4 * 4);
    #pragma unroll
    for (int i = 0; i < 8; ++i)
        pb[i] = *(const f32x2*)(Sg + (size_t)(kb * 8 + i) * D_ + db * 2);

    for (int kt = 0; kt < NKT; ++kt) {
        // ---- convert & stage to LDS ----
        #pragma unroll
        for (int rr = 0; rr < 2; ++rr) {
            const int row = a_r + rr * 32;
            s16x4 h, l;
            cvt_hilo4(pa[rr], h, l);
            const int col = (((a_c4 >> 1) ^ (row & 7)) << 3) + (a_c4 & 1) * 4;
            *(s16x4*)&As_hi[row][col] = h;
            *(s16x4*)&As_lo[row][col] = l;
        }
        #pragma unroll
        for (int dd = 0; dd < 2; ++dd) {
            const int row = db * 2 + dd;
            s16x8 h, l;
            #pragma unroll
            for (int j = 0; j < 8; ++j) {
                short hh, ll; cvt_hilo1(pb[j][dd], hh, ll);
                h[j] = hh; l[j] = ll;
            }
            const int key = (db & 3) | (((db >> 2) & 1) << 2);   // == ((row>>1)&3)|(((row>>3)&1)<<2)
            const int col = (kb ^ key) << 3;
            *(s16x8*)&Bs_hi[row][col] = h;
            *(s16x8*)&Bs_lo[row][col] = l;
        }
        __syncthreads();

        // ---- prefetch next tile's globals (completes during MFMA phase) ----
        if (kt + 1 < NKT) {
            const int k0 = (kt + 1) * BK;
            #pragma unroll
            for (int rr = 0; rr < 2; ++rr)
                pa[rr] = *(const f32x4*)(Ag + (size_t)(a_r + rr * 32) * L_ + k0 + a_c4 * 4);
            #pragma unroll
            for (int i = 0; i < 8; ++i)
                pb[i] = *(const f32x2*)(Sg + (size_t)(k0 + kb * 8 + i) * D_ + db * 2);
        }

        // ---- MFMA: 3-pass hi/lo split ----
        #pragma unroll
        for (int kc = 0; kc < 2; ++kc) {
            const int gbase = kc * 4;
            s16x8 ah[2], al[2], bh[2], bl[2];
            #pragma unroll
            for (int mi = 0; mi < 2; ++mi) {
                const int row = eo + mi * 16 + ml;
                const int col = ((gbase + kg) ^ (row & 7)) << 3;
                ah[mi] = *(const s16x8*)&As_hi[row][col];
                al[mi] = *(const s16x8*)&As_lo[row][col];
            }
            #pragma unroll
            for (int ni = 0; ni < 2; ++ni) {
                const int row = dq + ni * 16 + ml;
                const int keyB = ((row >> 1) & 3) | (((row >> 3) & 1) << 2);
                const int col  = ((gbase + kg) ^ keyB) << 3;
                bh[ni] = *(const s16x8*)&Bs_hi[row][col];
                bl[ni] = *(const s16x8*)&Bs_lo[row][col];
            }
            #pragma unroll
            for (int mi = 0; mi < 2; ++mi)
                #pragma unroll
                for (int ni = 0; ni < 2; ++ni) {
                    acc[mi][ni] = __builtin_amdgcn_mfma_f32_16x16x32_bf16(ah[mi], bh[ni], acc[mi][ni], 0, 0, 0);
                    acc[mi][ni] = __builtin_amdgcn_mfma_f32_16x16x32_bf16(ah[mi], bl[ni], acc[mi][ni], 0, 0, 0);
                    acc[mi][ni] = __builtin_amdgcn_mfma_f32_16x16x32_bf16(al[mi], bh[ni], acc[mi][ni], 0, 0, 0);
                }
        }
        __syncthreads();
    }

    if (WS) {
        // ---- plain coalesced stores of partials into ws[ks][b][e][d] (R6-proven) ----
        float* wsb = wsp + (size_t)ks * SLAB_FLOATS;
        #pragma unroll
        for (int mi = 0; mi < 2; ++mi) {
            #pragma unroll
            for (int rr = 0; rr < 4; ++rr) {
                const int er = eo + mi * 16 + kg * 4 + rr;
                #pragma unroll
                for (int ni = 0; ni < 2; ++ni)
                    wsb[((size_t)(b * E_ + e0 + er)) * D_ + d0 + dq + ni * 16 + ml] =
                        acc[mi][ni][rr];
            }
        }
    } else {
        // ---- fallback: atomic accumulation (R0 path) ----
        #pragma unroll
        for (int mi = 0; mi < 2; ++mi) {
            #pragma unroll
            for (int rr = 0; rr < 4; ++rr) {
                const int er = eo + mi * 16 + kg * 4 + rr;
                const float lv = lens_s[er];
                #pragma unroll
                for (int ni = 0; ni < 2; ++ni)
                    atomicAdd(&out[((size_t)(b * E_ + e0 + er)) * D_ + d0 + dq + ni * 16 + ml],
                              acc[mi][ni][rr] / lv);
            }
        }
    }
}

extern "C" void kernel_launch(void* const* d_in, const int* in_sizes, int n_in,
                              void* d_out, int out_size, void* d_ws, size_t ws_size,
                              hipStream_t stream) {
    const float* doc  = (const float*)d_in[0];   // [32][2048][256]
    const float* emap = (const float*)d_in[1];   // [32][256][2048]
    const float* lens = (const float*)d_in[2];   // [32][256]
    float* out = (float*)d_out;                  // [32][256][256]
    float* ws  = (float*)d_ws;

    dim3 grid(B_ * (E_ / BE) * (D_ / BD) * KS);  // 1024 workgroups, ~3 blocks/CU
    dim3 block(512);

    if (ws_size >= (size_t)WS_NEED) {
        // no atomics: partials -> workspace slabs, then streaming reduce
        hipLaunchKernelGGL((mean_pool_kernel<1>), grid, block, 0, stream,
                           doc, emap, lens, out, ws);
        hipLaunchKernelGGL(reduce_kernel,
                           dim3((unsigned)(SLAB_FLOATS / 4 / 256)), dim3(256), 0, stream,
                           (const f32x4*)ws, lens, (f32x4*)out);
    } else {
        // fallback: proven atomic path
        zero_out_kernel<<<dim3(out_size / (4 * 256)), dim3(256), 0, stream>>>((f32x4*)out);
        hipLaunchKernelGGL((mean_pool_kernel<0>), grid, block, 0, stream,
                           doc, emap, lens, out, ws);
    }
}